// Round 21
// baseline (57.544 us; speedup 1.0000x reference)
//
#include <hip/hip_runtime.h>
#include <hip/hip_bf16.h>
#include <math.h>
#include <string.h>

#define BB   16
#define NN   128
#define NCC  32
#define HH   256
#define AA   64
#define DEGN 3
#define BNR  (BB*NN)   // 2048 rows

typedef __bf16 bf16x8 __attribute__((ext_vector_type(8)));
typedef float  f32x16 __attribute__((ext_vector_type(16)));

__device__ __forceinline__ unsigned int pk2(float lo, float hi) {
    __hip_bfloat162 h2 = __float22bfloat162_rn(make_float2(lo, hi));
    unsigned int u;
    memcpy(&u, &h2, 4);
    return u;
}
__device__ __forceinline__ float2 unpk(unsigned int u) {
    return make_float2(__uint_as_float(u << 16),
                       __uint_as_float(u & 0xffff0000u));
}
__device__ __forceinline__ unsigned short bfbits(float f) {
    __hip_bfloat16 h = __float2bfloat16(f);
    unsigned short u;
    memcpy(&u, &h, 2);
    return u;
}

// ---------------------------------------------------------------------------
// Kernel 1 (k_head): fused prep (unchanged from round 9).
// ---------------------------------------------------------------------------
__global__ __launch_bounds__(256) void k_head(const float* __restrict__ cond,
                                              const float* __restrict__ cmask,
                                              const float* __restrict__ Wc,
                                              const float* __restrict__ W1,
                                              const float* __restrict__ Wlin,
                                              float* __restrict__ dv,
                                              float* __restrict__ dv_out,
                                              unsigned short* __restrict__ W1t,
                                              unsigned short* __restrict__ Wlt) {
    __shared__ float shm[32 * 33];
    const int bid = blockIdx.x, t = threadIdx.x;

    if (bid < 48) {
        const int d = bid >> 4, b = bid & 15;
        float s = 0.f, ms = 0.f;
        for (int c = 0; c < NCC; ++c) {
            float mk = cmask[b * NCC + c];
            s  += cond[(b * NCC + c) * HH + t] * mk;
            ms += mk;
        }
        shm[t] = s / fmaxf(ms, 1.0f);
        __syncthreads();
        const float* Wd = Wc + (size_t)d * HH * HH;
        float acc = 0.f;
        for (int k = 0; k < HH; ++k) acc += shm[k] * Wd[k * HH + t];
        int idx = (d * BB + b) * HH + t;
        dv[idx]     = acc;
        dv_out[idx] = acc;
    } else if (bid < 240) {
        const int q = bid - 48;
        const int d = q >> 6, r2 = q & 63, tk = r2 >> 3, tn = r2 & 7;
        float (*tile)[33] = (float (*)[33])shm;
        #pragma unroll
        for (int p = 0; p < 4; ++p) {
            int kr = p * 8 + (t >> 5), nr = t & 31;
            tile[kr][nr] = W1[((size_t)d * HH + tk * 32 + kr) * HH + tn * 32 + nr];
        }
        __syncthreads();
        #pragma unroll
        for (int p = 0; p < 4; ++p) {
            int nr = p * 8 + (t >> 5), kr = t & 31;
            W1t[((size_t)d * HH + tn * 32 + nr) * HH + tk * 32 + kr] =
                bfbits(tile[kr][nr]);
        }
    } else {
        const int q = bid - 240;
        const int d = q >> 4, r3 = q & 15, tk = r3 >> 1, ta = r3 & 1;
        float (*tile)[33] = (float (*)[33])shm;
        #pragma unroll
        for (int p = 0; p < 4; ++p) {
            int kr = p * 8 + (t >> 5), ar = t & 31;
            tile[kr][ar] = Wlin[((size_t)d * HH + tk * 32 + kr) * AA + ta * 32 + ar];
        }
        __syncthreads();
        #pragma unroll
        for (int p = 0; p < 4; ++p) {
            int ar = p * 8 + (t >> 5), kr = t & 31;
            Wlt[((size_t)d * AA + ta * 32 + ar) * HH + tk * 32 + kr] =
                bfbits(tile[kr][ar]);
        }
    }
}

// ---------------------------------------------------------------------------
// Kernel 2 (k_mlp): fused encoder+linear via bf16 MFMA (unchanged from r9).
// ---------------------------------------------------------------------------
__global__ __launch_bounds__(256) void k_mlp(const float* __restrict__ x,
                                             const float* __restrict__ xmask,
                                             const float* __restrict__ b1,
                                             const float* __restrict__ blin,
                                             const float* __restrict__ dv,
                                             const unsigned short* __restrict__ W1t,
                                             const unsigned short* __restrict__ Wlt,
                                             float* __restrict__ yv) {
    __shared__ __align__(16) char ldsA[32 * 512];
    __shared__ float ps[2][32][68];

    const int t = threadIdx.x;
    const int d = blockIdx.x >> 6, rt = blockIdx.x & 63;
    const int row0 = rt * 32;
    const int b = row0 >> 7;
    const int lane = t & 63, wid = t >> 6;
    const int rl5 = lane & 31, h2v = lane >> 5;

    #pragma unroll
    for (int it = 0; it < 8; ++it) {
        const int r = wid * 8 + it;
        const float4 v = *(const float4*)&x[(size_t)(row0 + r) * HH + lane * 4];
        uint2 u = make_uint2(pk2(v.x, v.y), pk2(v.z, v.w));
        *(uint2*)(ldsA + r * 512 + ((lane * 8) ^ ((r & 7) << 4))) = u;
    }
    __syncthreads();

    f32x16 acc1[2];
    #pragma unroll
    for (int nt = 0; nt < 2; ++nt)
        #pragma unroll
        for (int e = 0; e < 16; ++e) acc1[nt][e] = 0.f;

    #pragma unroll
    for (int ks = 0; ks < 16; ++ks) {
        bf16x8 af = *(const bf16x8*)(ldsA + rl5 * 512 +
                      ((ks * 32 + h2v * 16) ^ ((rl5 & 7) << 4)));
        #pragma unroll
        for (int nt = 0; nt < 2; ++nt) {
            const int n = wid * 64 + nt * 32 + rl5;
            bf16x8 bf = *(const bf16x8*)(W1t +
                          ((size_t)d * HH + n) * HH + ks * 16 + h2v * 8);
            acc1[nt] = __builtin_amdgcn_mfma_f32_32x32x16_bf16(af, bf, acc1[nt], 0, 0, 0);
        }
    }
    __syncthreads();

    #pragma unroll
    for (int nt = 0; nt < 2; ++nt) {
        const int col = wid * 64 + nt * 32 + rl5;
        const float add = b1[d * HH + col] + dv[(d * BB + b) * HH + col];
        #pragma unroll
        for (int e = 0; e < 16; ++e) {
            const int row = (e & 3) + 8 * (e >> 2) + 4 * h2v;
            float v = acc1[nt][e] + add;
            float u = 0.7978845608028654f * (v + 0.044715f * v * v * v);
            float g = 0.5f * v * (1.0f + tanhf(u));
            *(unsigned short*)(ldsA + row * 512 + ((col * 2) ^ ((row & 7) << 4))) =
                bfbits(g);
        }
    }
    __syncthreads();

    const int qc = wid >> 1, kh = wid & 1;
    f32x16 acc2;
    #pragma unroll
    for (int e = 0; e < 16; ++e) acc2[e] = 0.f;
    #pragma unroll
    for (int ks = 0; ks < 8; ++ks) {
        const int kk = kh * 8 + ks;
        bf16x8 af = *(const bf16x8*)(ldsA + rl5 * 512 +
                      ((kk * 32 + h2v * 16) ^ ((rl5 & 7) << 4)));
        bf16x8 bf = *(const bf16x8*)(Wlt +
                      ((size_t)d * AA + qc * 32 + rl5) * HH + kk * 16 + h2v * 8);
        acc2 = __builtin_amdgcn_mfma_f32_32x32x16_bf16(af, bf, acc2, 0, 0, 0);
    }
    #pragma unroll
    for (int e = 0; e < 16; ++e) {
        const int row = (e & 3) + 8 * (e >> 2) + 4 * h2v;
        ps[kh][row][qc * 32 + rl5] = acc2[e];
    }
    __syncthreads();

    #pragma unroll
    for (int j = 0; j < 8; ++j) {
        const int idx = t * 8 + j;
        const int row = idx >> 6, a = idx & 63;
        float v = ps[0][row][a] + ps[1][row][a] + blin[d * AA + a];
        v *= xmask[row0 + row];
        yv[((size_t)d * BNR + row0 + row) * AA + a] = v;
    }
}

// ---------------------------------------------------------------------------
// Kernel 3 (k_contract): r16 optimum + CO-RESIDENT BLOCK STAGGER.
// Grid 512 = exactly 2 blocks/CU, both launched at t=0 with identical
// instruction streams -> they phase-lock by SYMMETRY (no shared barrier
// needed): both burst stores simultaneously, both do LDS simultaneously ->
// the measured additivity of LDS-phase (~18us) and store-drain (~22us).
// Fix: one block of each co-resident pair sleeps ~half an xi period
// (~6us = 15 x s_sleep 15) before starting, anti-phasing the pair so one's
// store burst lands in the other's LDS/MFMA phase. Pair selection
// ((bid>>8)^bid)&1 staggers exactly one of each pair under BOTH plausible
// dispatch mappings ((i,i+256) round-robin and (2c,2c+1) linear).
// Everything else byte-identical to r16/r20 (absmax must stay 4.8828125e-4).
// ---------------------------------------------------------------------------
__device__ __forceinline__ void lds_fence_barrier() {
    asm volatile("s_waitcnt lgkmcnt(0)" ::: "memory");
    __builtin_amdgcn_s_barrier();
    __builtin_amdgcn_sched_barrier(0);
}

#define LROW 128   // bytes per LDS row (64 bf16)
#define SWZ(r) ((((r) >> 2) & 7) << 4)

__global__ __launch_bounds__(256, 2) void k_contract(const float* __restrict__ yv,
                                                     float* __restrict__ outp) {
    __shared__ __align__(16) char lds[5 * 128 * LROW];   // 80KB
    char* A1b = lds;
    char* A2b = lds + 1 * 128 * LROW;
    char* Y0b = lds + 2 * 128 * LROW;
    char* B1b = lds + 3 * 128 * LROW;    // = Y2
    char* B2b = lds + 4 * 128 * LROW;    // = Y1

    const int t  = threadIdx.x;
    const int b  = blockIdx.x >> 5;
    const int xg = blockIdx.x & 31;

    // ---- co-resident pair stagger: ~6us (half xi period) ----
    if (((blockIdx.x >> 8) ^ blockIdx.x) & 1) {
        #pragma unroll 1
        for (int i = 0; i < 15; ++i) asm volatile("s_sleep 15");
    }

    const float* y0p = yv + (size_t)(0 * BNR + b * NN) * AA;
    const float* y1p = yv + (size_t)(1 * BNR + b * NN) * AA;
    const float* y2p = yv + (size_t)(2 * BNR + b * NN) * AA;

    const int lane = t & 63;
    const int wid  = t >> 6;
    const int li   = lane & 31;
    const int rh   = lane >> 5;
    const int rl5  = lane & 31, h2v = lane >> 5;
    const int wy   = wid * 32;            // this wave's output row stripe

    // ---- prologue: prefetch s for all 4 xi (loads BEFORE any store) ----
    float s0v[4], s1v[4], s2v[4];
    #pragma unroll
    for (int xi = 0; xi < 4; ++xi) {
        const int xr = xg * 4 + xi;
        s0v[xi] = y0p[xr * AA + lane];
        s1v[xi] = y1p[xr * AA + lane];
        s2v[xi] = y2p[xr * AA + lane];
    }

    // ---- prologue: stage Y0, B1=Y2, B2=Y1 as bf16 (once per block) ----
    #pragma unroll
    for (int it = 0; it < 16; ++it) {
        const int r   = wid * 32 + it * 2 + rh;
        const int off = r * LROW + ((4 * li) ^ SWZ(r));
        const float2 v0 = *(const float2*)&y0p[r * AA + 2 * li];
        const float2 v1 = *(const float2*)&y1p[r * AA + 2 * li];
        const float2 v2 = *(const float2*)&y2p[r * AA + 2 * li];
        *(unsigned int*)(Y0b + off) = pk2(v0.x, v0.y);
        *(unsigned int*)(B1b + off) = pk2(v2.x, v2.y);
        *(unsigned int*)(B2b + off) = pk2(v1.x, v1.y);
    }

    const float inv = 1.0f / 4096.0f;

    #pragma unroll
    for (int xi = 0; xi < 4; ++xi) {
        const int xr = xg * 4 + xi;
        const float s0a = __shfl(s0v[xi], 2 * li), s0b = __shfl(s0v[xi], 2 * li + 1);
        const float s1a = __shfl(s1v[xi], 2 * li), s1b = __shfl(s1v[xi], 2 * li + 1);
        const float s2a = __shfl(s2v[xi], 2 * li), s2b = __shfl(s2v[xi], 2 * li + 1);

        if (xi == 0) lds_fence_barrier();   // Y panels visible to all waves

        // ---- construct A1/A2 (own rows) from LDS — LGKM ops only ----
        #pragma unroll
        for (int it = 0; it < 16; ++it) {
            const int r   = wid * 32 + it * 2 + rh;
            const int off = r * LROW + ((4 * li) ^ SWZ(r));
            const float2 y0 = unpk(*(const unsigned int*)(Y0b + off));
            const float2 y1 = unpk(*(const unsigned int*)(B2b + off));
            *(unsigned int*)(A1b + off) =
                pk2(s0a * y1.x + s1a * y0.x, s0b * y1.y + s1b * y0.y);
            *(unsigned int*)(A2b + off) = pk2(s2a * y0.x, s2b * y0.y);
        }
        lds_fence_barrier();   // bar1: A staged

        // ---- MFMA, order p0,p1,p2,p3 x ks x ni (bit-identical math) ----
        f32x16 acc[4];
        #pragma unroll
        for (int ni = 0; ni < 4; ++ni)
            #pragma unroll
            for (int e = 0; e < 16; ++e) acc[ni][e] = 0.f;

        #pragma unroll
        for (int p = 0; p < 4; ++p) {
            const char* Ua = (p == 0) ? A1b : (p == 1) ? B1b : (p == 2) ? A2b : B2b;
            const char* Va = (p == 0) ? B1b : (p == 1) ? A1b : (p == 2) ? B2b : A2b;
            #pragma unroll
            for (int ks = 0; ks < 4; ++ks) {
                const int arow = wy + rl5;
                bf16x8 af = *(const bf16x8*)(Ua + arow * LROW +
                              ((ks * 32 + h2v * 16) ^ SWZ(arow)));
                #pragma unroll
                for (int ni = 0; ni < 4; ++ni) {
                    const int brow = 4 * rl5 + ni;      // permuted-B read
                    bf16x8 bf = *(const bf16x8*)(Va + brow * LROW +
                                  ((ks * 32 + h2v * 16) ^ SWZ(brow)));
                    acc[ni] = __builtin_amdgcn_mfma_f32_32x32x16_bf16(
                        af, bf, acc[ni], 0, 0, 0);
                }
            }
        }
        lds_fence_barrier();   // bar2: all A reads done -> next construct safe

        // ---- epilogue: direct full-row stores from registers ----
        float* osl = outp + ((size_t)(b * NN + xr)) * (NN * NN);
        #pragma unroll
        for (int e = 0; e < 16; ++e) {
            const int rowf = wy + (e & 3) + 8 * (e >> 2) + 4 * h2v;
            float4 v = make_float4(acc[0][e] * inv, acc[1][e] * inv,
                                   acc[2][e] * inv, acc[3][e] * inv);
            *(float4*)&osl[(size_t)rowf * NN + 4 * rl5] = v;
        }
    }
}

// ---------------------------------------------------------------------------
extern "C" void kernel_launch(void* const* d_in, const int* in_sizes, int n_in,
                              void* d_out, int out_size, void* d_ws, size_t ws_size,
                              hipStream_t stream) {
    const float* x     = (const float*)d_in[0];
    const float* xmask = (const float*)d_in[1];
    const float* cond  = (const float*)d_in[2];
    const float* cmask = (const float*)d_in[3];
    const float* W1    = (const float*)d_in[4];
    const float* b1    = (const float*)d_in[5];
    const float* Wc    = (const float*)d_in[6];
    const float* Wlin  = (const float*)d_in[7];
    const float* blin  = (const float*)d_in[8];

    float* out = (float*)d_out;
    float* ws  = (float*)d_ws;

    float* dv  = ws;                               // 3*16*256 f
    float* yv  = ws + 12288;                       // 3*2048*64 f
    unsigned short* W1t = (unsigned short*)((char*)d_ws + (size_t)(12288 + 393216) * 4);
    unsigned short* Wlt = W1t + (size_t)DEGN * HH * HH;
    float* dv_out = out + (size_t)BB * NN * NN * NN;

    k_head    <<<dim3(288), dim3(256), 0, stream>>>(cond, cmask, Wc, W1, Wlin,
                                                    dv, dv_out, W1t, Wlt);
    k_mlp     <<<dim3(DEGN * 64), dim3(256), 0, stream>>>(x, xmask, b1, blin, dv,
                                                          W1t, Wlt, yv);
    k_contract<<<dim3(BB * NN / 4), dim3(256), 0, stream>>>(yv, out);
}

// Round 22
// 55.263 us; speedup vs baseline: 1.0413x; 1.0413x over previous
//
#include <hip/hip_runtime.h>
#include <hip/hip_bf16.h>
#include <math.h>
#include <string.h>

#define BB   16
#define NN   128
#define NCC  32
#define HH   256
#define AA   64
#define DEGN 3
#define BNR  (BB*NN)   // 2048 rows

typedef __bf16 bf16x8 __attribute__((ext_vector_type(8)));
typedef float  f32x16 __attribute__((ext_vector_type(16)));

__device__ __forceinline__ unsigned int pk2(float lo, float hi) {
    __hip_bfloat162 h2 = __float22bfloat162_rn(make_float2(lo, hi));
    unsigned int u;
    memcpy(&u, &h2, 4);
    return u;
}
__device__ __forceinline__ float2 unpk(unsigned int u) {
    return make_float2(__uint_as_float(u << 16),
                       __uint_as_float(u & 0xffff0000u));
}
__device__ __forceinline__ unsigned short bfbits(float f) {
    __hip_bfloat16 h = __float2bfloat16(f);
    unsigned short u;
    memcpy(&u, &h, 2);
    return u;
}

// ---------------------------------------------------------------------------
// Kernel 1 (k_head): fused prep (unchanged from round 9).
// ---------------------------------------------------------------------------
__global__ __launch_bounds__(256) void k_head(const float* __restrict__ cond,
                                              const float* __restrict__ cmask,
                                              const float* __restrict__ Wc,
                                              const float* __restrict__ W1,
                                              const float* __restrict__ Wlin,
                                              float* __restrict__ dv,
                                              float* __restrict__ dv_out,
                                              unsigned short* __restrict__ W1t,
                                              unsigned short* __restrict__ Wlt) {
    __shared__ float shm[32 * 33];
    const int bid = blockIdx.x, t = threadIdx.x;

    if (bid < 48) {
        const int d = bid >> 4, b = bid & 15;
        float s = 0.f, ms = 0.f;
        for (int c = 0; c < NCC; ++c) {
            float mk = cmask[b * NCC + c];
            s  += cond[(b * NCC + c) * HH + t] * mk;
            ms += mk;
        }
        shm[t] = s / fmaxf(ms, 1.0f);
        __syncthreads();
        const float* Wd = Wc + (size_t)d * HH * HH;
        float acc = 0.f;
        for (int k = 0; k < HH; ++k) acc += shm[k] * Wd[k * HH + t];
        int idx = (d * BB + b) * HH + t;
        dv[idx]     = acc;
        dv_out[idx] = acc;
    } else if (bid < 240) {
        const int q = bid - 48;
        const int d = q >> 6, r2 = q & 63, tk = r2 >> 3, tn = r2 & 7;
        float (*tile)[33] = (float (*)[33])shm;
        #pragma unroll
        for (int p = 0; p < 4; ++p) {
            int kr = p * 8 + (t >> 5), nr = t & 31;
            tile[kr][nr] = W1[((size_t)d * HH + tk * 32 + kr) * HH + tn * 32 + nr];
        }
        __syncthreads();
        #pragma unroll
        for (int p = 0; p < 4; ++p) {
            int nr = p * 8 + (t >> 5), kr = t & 31;
            W1t[((size_t)d * HH + tn * 32 + nr) * HH + tk * 32 + kr] =
                bfbits(tile[kr][nr]);
        }
    } else {
        const int q = bid - 240;
        const int d = q >> 4, r3 = q & 15, tk = r3 >> 1, ta = r3 & 1;
        float (*tile)[33] = (float (*)[33])shm;
        #pragma unroll
        for (int p = 0; p < 4; ++p) {
            int kr = p * 8 + (t >> 5), ar = t & 31;
            tile[kr][ar] = Wlin[((size_t)d * HH + tk * 32 + kr) * AA + ta * 32 + ar];
        }
        __syncthreads();
        #pragma unroll
        for (int p = 0; p < 4; ++p) {
            int ar = p * 8 + (t >> 5), kr = t & 31;
            Wlt[((size_t)d * AA + ta * 32 + ar) * HH + tk * 32 + kr] =
                bfbits(tile[kr][ar]);
        }
    }
}

// ---------------------------------------------------------------------------
// Kernel 2 (k_mlp): fused encoder+linear via bf16 MFMA (unchanged from r9).
// ---------------------------------------------------------------------------
__global__ __launch_bounds__(256) void k_mlp(const float* __restrict__ x,
                                             const float* __restrict__ xmask,
                                             const float* __restrict__ b1,
                                             const float* __restrict__ blin,
                                             const float* __restrict__ dv,
                                             const unsigned short* __restrict__ W1t,
                                             const unsigned short* __restrict__ Wlt,
                                             float* __restrict__ yv) {
    __shared__ __align__(16) char ldsA[32 * 512];
    __shared__ float ps[2][32][68];

    const int t = threadIdx.x;
    const int d = blockIdx.x >> 6, rt = blockIdx.x & 63;
    const int row0 = rt * 32;
    const int b = row0 >> 7;
    const int lane = t & 63, wid = t >> 6;
    const int rl5 = lane & 31, h2v = lane >> 5;

    #pragma unroll
    for (int it = 0; it < 8; ++it) {
        const int r = wid * 8 + it;
        const float4 v = *(const float4*)&x[(size_t)(row0 + r) * HH + lane * 4];
        uint2 u = make_uint2(pk2(v.x, v.y), pk2(v.z, v.w));
        *(uint2*)(ldsA + r * 512 + ((lane * 8) ^ ((r & 7) << 4))) = u;
    }
    __syncthreads();

    f32x16 acc1[2];
    #pragma unroll
    for (int nt = 0; nt < 2; ++nt)
        #pragma unroll
        for (int e = 0; e < 16; ++e) acc1[nt][e] = 0.f;

    #pragma unroll
    for (int ks = 0; ks < 16; ++ks) {
        bf16x8 af = *(const bf16x8*)(ldsA + rl5 * 512 +
                      ((ks * 32 + h2v * 16) ^ ((rl5 & 7) << 4)));
        #pragma unroll
        for (int nt = 0; nt < 2; ++nt) {
            const int n = wid * 64 + nt * 32 + rl5;
            bf16x8 bf = *(const bf16x8*)(W1t +
                          ((size_t)d * HH + n) * HH + ks * 16 + h2v * 8);
            acc1[nt] = __builtin_amdgcn_mfma_f32_32x32x16_bf16(af, bf, acc1[nt], 0, 0, 0);
        }
    }
    __syncthreads();

    #pragma unroll
    for (int nt = 0; nt < 2; ++nt) {
        const int col = wid * 64 + nt * 32 + rl5;
        const float add = b1[d * HH + col] + dv[(d * BB + b) * HH + col];
        #pragma unroll
        for (int e = 0; e < 16; ++e) {
            const int row = (e & 3) + 8 * (e >> 2) + 4 * h2v;
            float v = acc1[nt][e] + add;
            float u = 0.7978845608028654f * (v + 0.044715f * v * v * v);
            float g = 0.5f * v * (1.0f + tanhf(u));
            *(unsigned short*)(ldsA + row * 512 + ((col * 2) ^ ((row & 7) << 4))) =
                bfbits(g);
        }
    }
    __syncthreads();

    const int qc = wid >> 1, kh = wid & 1;
    f32x16 acc2;
    #pragma unroll
    for (int e = 0; e < 16; ++e) acc2[e] = 0.f;
    #pragma unroll
    for (int ks = 0; ks < 8; ++ks) {
        const int kk = kh * 8 + ks;
        bf16x8 af = *(const bf16x8*)(ldsA + rl5 * 512 +
                      ((kk * 32 + h2v * 16) ^ ((rl5 & 7) << 4)));
        bf16x8 bf = *(const bf16x8*)(Wlt +
                      ((size_t)d * AA + qc * 32 + rl5) * HH + kk * 16 + h2v * 8);
        acc2 = __builtin_amdgcn_mfma_f32_32x32x16_bf16(af, bf, acc2, 0, 0, 0);
    }
    #pragma unroll
    for (int e = 0; e < 16; ++e) {
        const int row = (e & 3) + 8 * (e >> 2) + 4 * h2v;
        ps[kh][row][qc * 32 + rl5] = acc2[e];
    }
    __syncthreads();

    #pragma unroll
    for (int j = 0; j < 8; ++j) {
        const int idx = t * 8 + j;
        const int row = idx >> 6, a = idx & 63;
        float v = ps[0][row][a] + ps[1][row][a] + blin[d * AA + a];
        v *= xmask[row0 + row];
        yv[((size_t)d * BNR + row0 + row) * AA + a] = v;
    }
}

// ---------------------------------------------------------------------------
// Kernel 3 (k_contract): r16 optimum, verbatim (best: 55.29-55.31 us total).
// out*4096 = A1 B1^T + B1 A1^T + A2 B2^T + B2 A2^T per (b,x).
// Zero global loads in the xi loop; A1/A2 constructed in LDS from bf16
// Y panels; bf read from LDS row 4*rl5+ni so lane rl5 holds problem cols
// {4rl5..4rl5+3} in acc[0..3][e] -> direct full-row float4 stores, no
// epilogue LDS bounce. SWZ ((r>>2)&7)<<4. 80KB LDS, 2 blocks/CU, VGPR 88.
// ---------------------------------------------------------------------------
__device__ __forceinline__ void lds_fence_barrier() {
    asm volatile("s_waitcnt lgkmcnt(0)" ::: "memory");
    __builtin_amdgcn_s_barrier();
    __builtin_amdgcn_sched_barrier(0);
}

#define LROW 128   // bytes per LDS row (64 bf16)
#define SWZ(r) ((((r) >> 2) & 7) << 4)

__global__ __launch_bounds__(256, 2) void k_contract(const float* __restrict__ yv,
                                                     float* __restrict__ outp) {
    __shared__ __align__(16) char lds[5 * 128 * LROW];   // 80KB
    char* A1b = lds;
    char* A2b = lds + 1 * 128 * LROW;
    char* Y0b = lds + 2 * 128 * LROW;
    char* B1b = lds + 3 * 128 * LROW;    // = Y2
    char* B2b = lds + 4 * 128 * LROW;    // = Y1

    const int t  = threadIdx.x;
    const int b  = blockIdx.x >> 5;
    const int xg = blockIdx.x & 31;

    const float* y0p = yv + (size_t)(0 * BNR + b * NN) * AA;
    const float* y1p = yv + (size_t)(1 * BNR + b * NN) * AA;
    const float* y2p = yv + (size_t)(2 * BNR + b * NN) * AA;

    const int lane = t & 63;
    const int wid  = t >> 6;
    const int li   = lane & 31;
    const int rh   = lane >> 5;
    const int rl5  = lane & 31, h2v = lane >> 5;
    const int wy   = wid * 32;            // this wave's output row stripe

    // ---- prologue: prefetch s for all 4 xi (loads BEFORE any store) ----
    float s0v[4], s1v[4], s2v[4];
    #pragma unroll
    for (int xi = 0; xi < 4; ++xi) {
        const int xr = xg * 4 + xi;
        s0v[xi] = y0p[xr * AA + lane];
        s1v[xi] = y1p[xr * AA + lane];
        s2v[xi] = y2p[xr * AA + lane];
    }

    // ---- prologue: stage Y0, B1=Y2, B2=Y1 as bf16 (once per block) ----
    #pragma unroll
    for (int it = 0; it < 16; ++it) {
        const int r   = wid * 32 + it * 2 + rh;
        const int off = r * LROW + ((4 * li) ^ SWZ(r));
        const float2 v0 = *(const float2*)&y0p[r * AA + 2 * li];
        const float2 v1 = *(const float2*)&y1p[r * AA + 2 * li];
        const float2 v2 = *(const float2*)&y2p[r * AA + 2 * li];
        *(unsigned int*)(Y0b + off) = pk2(v0.x, v0.y);
        *(unsigned int*)(B1b + off) = pk2(v2.x, v2.y);
        *(unsigned int*)(B2b + off) = pk2(v1.x, v1.y);
    }

    const float inv = 1.0f / 4096.0f;

    #pragma unroll
    for (int xi = 0; xi < 4; ++xi) {
        const int xr = xg * 4 + xi;
        const float s0a = __shfl(s0v[xi], 2 * li), s0b = __shfl(s0v[xi], 2 * li + 1);
        const float s1a = __shfl(s1v[xi], 2 * li), s1b = __shfl(s1v[xi], 2 * li + 1);
        const float s2a = __shfl(s2v[xi], 2 * li), s2b = __shfl(s2v[xi], 2 * li + 1);

        if (xi == 0) lds_fence_barrier();   // Y panels visible to all waves

        // ---- construct A1/A2 (own rows) from LDS — LGKM ops only ----
        #pragma unroll
        for (int it = 0; it < 16; ++it) {
            const int r   = wid * 32 + it * 2 + rh;
            const int off = r * LROW + ((4 * li) ^ SWZ(r));
            const float2 y0 = unpk(*(const unsigned int*)(Y0b + off));
            const float2 y1 = unpk(*(const unsigned int*)(B2b + off));
            *(unsigned int*)(A1b + off) =
                pk2(s0a * y1.x + s1a * y0.x, s0b * y1.y + s1b * y0.y);
            *(unsigned int*)(A2b + off) = pk2(s2a * y0.x, s2b * y0.y);
        }
        lds_fence_barrier();   // bar1: A staged

        // ---- MFMA, order p0,p1,p2,p3 x ks x ni (bit-identical math) ----
        f32x16 acc[4];
        #pragma unroll
        for (int ni = 0; ni < 4; ++ni)
            #pragma unroll
            for (int e = 0; e < 16; ++e) acc[ni][e] = 0.f;

        #pragma unroll
        for (int p = 0; p < 4; ++p) {
            const char* Ua = (p == 0) ? A1b : (p == 1) ? B1b : (p == 2) ? A2b : B2b;
            const char* Va = (p == 0) ? B1b : (p == 1) ? A1b : (p == 2) ? B2b : A2b;
            #pragma unroll
            for (int ks = 0; ks < 4; ++ks) {
                const int arow = wy + rl5;
                bf16x8 af = *(const bf16x8*)(Ua + arow * LROW +
                              ((ks * 32 + h2v * 16) ^ SWZ(arow)));
                #pragma unroll
                for (int ni = 0; ni < 4; ++ni) {
                    const int brow = 4 * rl5 + ni;      // permuted-B read
                    bf16x8 bf = *(const bf16x8*)(Va + brow * LROW +
                                  ((ks * 32 + h2v * 16) ^ SWZ(brow)));
                    acc[ni] = __builtin_amdgcn_mfma_f32_32x32x16_bf16(
                        af, bf, acc[ni], 0, 0, 0);
                }
            }
        }
        lds_fence_barrier();   // bar2: all A reads done -> next construct safe

        // ---- epilogue: direct full-row stores from registers ----
        // lane rl5 holds problem cols {4rl5..4rl5+3} in acc[0..3][e];
        // row = wy + (e&3) + 8*(e>>2) + 4*h2v. One float4/lane = 512B/half-wave
        // = one full output row. No LDS, no waits; stores drain under next xi.
        float* osl = outp + ((size_t)(b * NN + xr)) * (NN * NN);
        #pragma unroll
        for (int e = 0; e < 16; ++e) {
            const int rowf = wy + (e & 3) + 8 * (e >> 2) + 4 * h2v;
            float4 v = make_float4(acc[0][e] * inv, acc[1][e] * inv,
                                   acc[2][e] * inv, acc[3][e] * inv);
            *(float4*)&osl[(size_t)rowf * NN + 4 * rl5] = v;
        }
    }
}

// ---------------------------------------------------------------------------
extern "C" void kernel_launch(void* const* d_in, const int* in_sizes, int n_in,
                              void* d_out, int out_size, void* d_ws, size_t ws_size,
                              hipStream_t stream) {
    const float* x     = (const float*)d_in[0];
    const float* xmask = (const float*)d_in[1];
    const float* cond  = (const float*)d_in[2];
    const float* cmask = (const float*)d_in[3];
    const float* W1    = (const float*)d_in[4];
    const float* b1    = (const float*)d_in[5];
    const float* Wc    = (const float*)d_in[6];
    const float* Wlin  = (const float*)d_in[7];
    const float* blin  = (const float*)d_in[8];

    float* out = (float*)d_out;
    float* ws  = (float*)d_ws;

    float* dv  = ws;                               // 3*16*256 f
    float* yv  = ws + 12288;                       // 3*2048*64 f
    unsigned short* W1t = (unsigned short*)((char*)d_ws + (size_t)(12288 + 393216) * 4);
    unsigned short* Wlt = W1t + (size_t)DEGN * HH * HH;
    float* dv_out = out + (size_t)BB * NN * NN * NN;

    k_head    <<<dim3(288), dim3(256), 0, stream>>>(cond, cmask, Wc, W1, Wlin,
                                                    dv, dv_out, W1t, Wlt);
    k_mlp     <<<dim3(DEGN * 64), dim3(256), 0, stream>>>(x, xmask, b1, blin, dv,
                                                          W1t, Wlt, yv);
    k_contract<<<dim3(BB * NN / 4), dim3(256), 0, stream>>>(yv, out);
}